// Round 16
// baseline (1145.455 us; speedup 1.0000x reference)
//
#include <hip/hip_runtime.h>

// Seq2SeqDecoder GRU+attention decoder, B=32 T=64 S=128.
// R16: dual-chain interleave. 128 blocks; block (g=bid>>4, p=bid&15) serves
// chains b=2p,2p+1 (same j-slice g). Per step: ph1_A,ph1_B,ph2_A,ph2_B --
// each publish consumed one compute-phase later -> exchange RT hidden.
// GEMMs back to 2-deep prefetch (R13 measured best).

constexpr int BB  = 32;
constexpr int TT  = 64;
constexpr int SS  = 128;
constexpr int DD  = 768;
constexpr int EE  = 1024;
constexpr int HH  = 512;
constexpr int G3  = 1536;
constexpr int II  = 1792;   // E2 + D
constexpr int CIN = 2304;   // H + E2 + D

typedef _Float16 half2_t __attribute__((ext_vector_type(2)));
typedef _Float16 half8_t __attribute__((ext_vector_type(8)));
typedef float f32x4_t __attribute__((ext_vector_type(4)));

__device__ __forceinline__ float fast_rcp(float x) { return __builtin_amdgcn_rcpf(x); }
__device__ __forceinline__ float tanh_f(float x) {
  float e = __expf(2.f * x);
  return 1.f - 2.f * fast_rcp(1.f + e);
}
__device__ __forceinline__ float sigmoid_f(float x) { return fast_rcp(1.f + __expf(-x)); }
__device__ __forceinline__ unsigned packh2(float x, float y) {
  half2_t h; h[0] = (_Float16)x; h[1] = (_Float16)y;
  return __builtin_bit_cast(unsigned, h);
}
__device__ __forceinline__ float h2lo(unsigned v) {
  return (float)__builtin_bit_cast(half2_t, v)[0];
}
__device__ __forceinline__ float h2hi(unsigned v) {
  return (float)__builtin_bit_cast(half2_t, v)[1];
}
__device__ __forceinline__ unsigned short f2h(float f) {
  _Float16 h = (_Float16)f; return __builtin_bit_cast(unsigned short, h);
}
__device__ __forceinline__ float u16tof(unsigned short u) {
  return (float)__builtin_bit_cast(_Float16, u);
}
__device__ __forceinline__ float fdot2(unsigned a, unsigned b, float c) {
#if __has_builtin(__builtin_amdgcn_fdot2)
  return __builtin_amdgcn_fdot2(__builtin_bit_cast(half2_t, a),
                                __builtin_bit_cast(half2_t, b), c, false);
#else
  half2_t ha = __builtin_bit_cast(half2_t, a);
  half2_t hb = __builtin_bit_cast(half2_t, b);
  return fmaf((float)ha[1], (float)hb[1], fmaf((float)ha[0], (float)hb[0], c));
#endif
}

__device__ __forceinline__ unsigned long long ald64(const unsigned long long* p) {
  return __hip_atomic_load(p, __ATOMIC_RELAXED, __HIP_MEMORY_SCOPE_AGENT);
}
__device__ __forceinline__ void ast64(unsigned long long* p, unsigned long long v) {
  __hip_atomic_store(p, v, __ATOMIC_RELAXED, __HIP_MEMORY_SCOPE_AGENT);
}
__device__ __forceinline__ unsigned long long mkchunk(unsigned pair, unsigned seq) {
  return (unsigned long long)pair | ((unsigned long long)seq << 32);
}

// ================= fused prep kernel ==========================================
constexpr int PB0 = 33;           // hx init (32) + ps zero (1)
constexpr int PB1 = PB0 + 2048;   // emb rows
constexpr int PB2 = PB1 + 2048;   // enc cast
constexpr int PB3 = PB2 + 384;    // whh cast
constexpr int PB4 = PB3 + 864;    // fcw cast
constexpr int PB5 = PB4 + 1536;   // wih768 pack
constexpr int PB6 = PB5 + 1536;   // wihw pack
constexpr int PB7 = PB6 + 256;    // wa tcast
constexpr int PB8 = PB7 + 512;    // waet tcast

__device__ __forceinline__ void cast8(const float* __restrict__ in,
                                      unsigned short* __restrict__ out,
                                      int blk, int tid) {
  int i = (blk * 256 + tid) * 8;
  float4 a = *(const float4*)(in + i);
  float4 b = *(const float4*)(in + i + 4);
  unsigned short r[8] = {f2h(a.x), f2h(a.y), f2h(a.z), f2h(a.w),
                         f2h(b.x), f2h(b.y), f2h(b.z), f2h(b.w)};
  *(uint4*)(out + i) = *(uint4*)r;
}
__device__ __forceinline__ void pack_row(const float* __restrict__ src, int srcld,
                                         unsigned short* __restrict__ dst, int W,
                                         int r, int tid) {
  const float* s = src + (size_t)r * srcld;
  unsigned short* d = dst + (size_t)r * W;
  for (int c = tid * 4; c < W; c += 256 * 4) {
    float4 v = *(const float4*)(s + c);
    unsigned short q[4] = {f2h(v.x), f2h(v.y), f2h(v.z), f2h(v.w)};
    *(unsigned long long*)(d + c) = *(unsigned long long*)q;
  }
}
__device__ __forceinline__ void tcast_tile(const float* __restrict__ in, int R,
                                           int C, unsigned short* __restrict__ out,
                                           int bx, int by, int tid, float (*t)[33]) {
  const int c0 = bx * 32, r0 = by * 32;
  const int tx = tid & 31, ty = tid >> 5;  // 32x8
  for (int dy = 0; dy < 32; dy += 8)
    t[ty + dy][tx] = in[(size_t)(r0 + ty + dy) * C + c0 + tx];
  __syncthreads();
  for (int dy = 0; dy < 32; dy += 8)
    out[(size_t)(c0 + ty + dy) * R + r0 + tx] = f2h(t[tx][ty + dy]);
}

__global__ __launch_bounds__(256) void prep_kernel(
    const int* __restrict__ ids, const float* __restrict__ embed_W,
    const float* __restrict__ enc_hidden, const float* __restrict__ enc_outputs,
    const float* __restrict__ attn_W, const float* __restrict__ W_ih,
    const float* __restrict__ W_hh, const float* __restrict__ fc_W,
    unsigned short* __restrict__ Xh, unsigned short* __restrict__ enc_h,
    unsigned short* __restrict__ whh_h, unsigned short* __restrict__ fcw_h,
    unsigned short* __restrict__ wih768, unsigned short* __restrict__ wihw_h,
    unsigned short* __restrict__ wa_t, unsigned short* __restrict__ waet,
    unsigned long long* __restrict__ hx, unsigned long long* __restrict__ ps)
{
  __shared__ float tbuf[32][33];
  const int bidx = blockIdx.x;
  const int tid = threadIdx.x;
  if (bidx < PB0) {
    int b = bidx;
    if (b < BB) {
      unsigned pair = packh2(enc_hidden[(size_t)b * HH + 2 * tid],
                             enc_hidden[(size_t)b * HH + 2 * tid + 1]);
      hx[(size_t)b * 256 + tid] = mkchunk(pair, 0u);
    } else {
      for (int i = tid; i < BB * 512; i += 256) ps[i] = 0ull;
    }
  } else if (bidx < PB1) {
    int row = bidx - PB0;
    int id = ids[row];                       // attention_mask all-ones
    const float scale = 27.712812921102035f; // sqrt(768)
    const float* src = embed_W + (size_t)id * DD;
    unsigned short* dst = Xh + (size_t)row * CIN + (HH + EE);
    for (int c = tid; c < DD; c += 256) dst[c] = f2h(src[c] * scale);
  } else if (bidx < PB2) {
    cast8(enc_outputs, enc_h, bidx - PB1, tid);
  } else if (bidx < PB3) {
    cast8(W_hh, whh_h, bidx - PB2, tid);
  } else if (bidx < PB4) {
    cast8(fc_W, fcw_h, bidx - PB3, tid);
  } else if (bidx < PB5) {
    pack_row(W_ih, II, wih768, DD, bidx - PB4, tid);
  } else if (bidx < PB6) {
    pack_row(W_ih + DD, II, wihw_h, EE, bidx - PB5, tid);
  } else if (bidx < PB7) {
    int q = bidx - PB6;
    tcast_tile(attn_W, HH, HH, wa_t, q & 15, q >> 4, tid, tbuf);
  } else {
    int q = bidx - PB7;
    tcast_tile(attn_W + (size_t)HH * HH, EE, HH, waet, q & 15, q >> 4, tid, tbuf);
  }
}

// ========== MFMA f16 128x128 tile, 2-deep register prefetch (R13 best) ========
template <bool F32OUT>
__device__ __forceinline__ void mfma_tile128(
    const unsigned short* __restrict__ Ah, int lda,
    const unsigned short* __restrict__ Bh, int ldb,
    const float* __restrict__ bias,
    unsigned short* __restrict__ Ch, float* __restrict__ Cf, int ldc, int K,
    int m0, int n0)
{
  const int lane = threadIdx.x & 63;
  const int wv = threadIdx.x >> 6;
  const int wr = wv >> 1, wc = wv & 1;          // 2x2 wave grid, 64x64 each
  const int rbase = m0 + wr * 64 + (lane & 15);
  const int cbase = n0 + wc * 64 + (lane & 15);
  const int koff = (lane >> 4) * 8;
  f32x4_t acc[4][4] = {};
  half8_t a[4], b[4];
#pragma unroll
  for (int i = 0; i < 4; ++i) {
    a[i] = *(const half8_t*)(Ah + (size_t)(rbase + i * 16) * lda + koff);
    b[i] = *(const half8_t*)(Bh + (size_t)(cbase + i * 16) * ldb + koff);
  }
  for (int k0 = 32; k0 < K; k0 += 32) {
    half8_t an[4], bn[4];
#pragma unroll
    for (int i = 0; i < 4; ++i) {
      an[i] = *(const half8_t*)(Ah + (size_t)(rbase + i * 16) * lda + k0 + koff);
      bn[i] = *(const half8_t*)(Bh + (size_t)(cbase + i * 16) * ldb + k0 + koff);
    }
#pragma unroll
    for (int mf = 0; mf < 4; ++mf)
#pragma unroll
      for (int nf = 0; nf < 4; ++nf)
        acc[mf][nf] =
            __builtin_amdgcn_mfma_f32_16x16x32_f16(a[mf], b[nf], acc[mf][nf], 0, 0, 0);
#pragma unroll
    for (int i = 0; i < 4; ++i) { a[i] = an[i]; b[i] = bn[i]; }
  }
#pragma unroll
  for (int mf = 0; mf < 4; ++mf)
#pragma unroll
    for (int nf = 0; nf < 4; ++nf)
      acc[mf][nf] =
          __builtin_amdgcn_mfma_f32_16x16x32_f16(a[mf], b[nf], acc[mf][nf], 0, 0, 0);
#pragma unroll
  for (int mf = 0; mf < 4; ++mf)
#pragma unroll
    for (int nf = 0; nf < 4; ++nf) {
      const int col = n0 + wc * 64 + nf * 16 + (lane & 15);
      const float bv = bias ? bias[col] : 0.f;
#pragma unroll
      for (int r = 0; r < 4; ++r) {
        const int rr = m0 + wr * 64 + mf * 16 + (lane >> 4) * 4 + r;
        if (F32OUT) Cf[(size_t)rr * ldc + col] = acc[mf][nf][r] + bv;
        else        Ch[(size_t)rr * ldc + col] = f2h(acc[mf][nf][r] + bv);
      }
    }
}

// fused pre-GEMMs: ep (128 blocks) | geh (192) | encW (384)
__global__ __launch_bounds__(256) void gemm3_kernel(
    const unsigned short* __restrict__ enc_h,
    const unsigned short* __restrict__ waet,
    const float* __restrict__ attn_b,
    unsigned short* __restrict__ ep_h,
    const unsigned short* __restrict__ Xh,
    const unsigned short* __restrict__ wih768,
    const float* __restrict__ b_ih,
    unsigned short* __restrict__ geh,
    const unsigned short* __restrict__ wihw_h,
    unsigned short* __restrict__ encW)
{
  const int id = blockIdx.x;
  if (id < 128) {               // ep: M=4096 N=512 K=1024 -> 32m x 4n
    int nt = id & 3, mt = id >> 2;
    mfma_tile128<false>(enc_h, EE, waet, EE, attn_b, ep_h, nullptr, HH, EE,
                        mt * 128, nt * 128);
  } else if (id < 320) {        // geh: M=2048 N=1536 K=768 -> 16m x 12n
    int q = id - 128, nt = q % 12, mt = q / 12;
    mfma_tile128<false>(Xh + (HH + EE), CIN, wih768, DD, b_ih, geh, nullptr,
                        G3, DD, mt * 128, nt * 128);
  } else {                      // encW: M=4096 N=1536 K=1024 -> 32m x 12n
    int q = id - 320, nt = q % 12, mt = q / 12;
    mfma_tile128<false>(enc_h, EE, wihw_h, EE, nullptr, encW, nullptr,
                        G3, EE, mt * 128, nt * 128);
  }
}

__global__ __launch_bounds__(256) void out_gemm_kernel(
    const unsigned short* __restrict__ Xh,
    const unsigned short* __restrict__ fcw_h,
    const float* __restrict__ fc_b, float* __restrict__ out)
{
  mfma_tile128<true>(Xh, CIN, fcw_h, CIN, fc_b, nullptr, out, DD, CIN,
                     blockIdx.y * 128, blockIdx.x * 128);
}

// ================= persistent recurrence: dual-chain interleave ===============
// 128 blocks: p = bid&15 (chain pair), g = bid>>4 (j-slice [64g,+64)).
// Chains b0=2p, b1=2p+1. Per step: ph1(A), ph1(B), ph2(A), ph2(B) -- each
// publish is consumed one compute-phase later, hiding the agent-RT.
__global__ __launch_bounds__(512, 1) void recur_kernel(
    const unsigned short* __restrict__ wa_t,   // [512 j][512 i] f16
    const unsigned short* __restrict__ whh_h,  // [1536 j'][512 i] f16
    const float* __restrict__ val_w,
    const float* __restrict__ b_hh,
    const unsigned* __restrict__ ep32,     // [B*S][256] f16 pairs (proj+attn_b)
    const unsigned* __restrict__ enc32,    // [B*S][512] f16 pairs
    const unsigned short* __restrict__ encW, // [B*S][1536] f16
    const unsigned short* __restrict__ geh,  // [B*T][1536] f16
    const float* __restrict__ enc_hidden,  // (B,H) f32
    unsigned long long* __restrict__ hx,   // [B][8][32] chunks [AGENT]
    unsigned long long* __restrict__ ps,   // [B][8][64] chunks [AGENT]
    unsigned short* __restrict__ Xh)       // [B*T][2304] f16 [h|wtd|emb]
{
  __shared__ unsigned s_encw[2][3][64][64]; // 96 KB (xor-swizzled on sp)
  __shared__ unsigned s_ep[2][SS][33];      // 33.8 KB
  __shared__ float s_p[4][8][64];           // 8 KB  (shared transient)
  __shared__ unsigned s_hwa2[32];
  __shared__ unsigned s_vw2[32];
  __shared__ unsigned s_ps[8][64];          // 2 KB
  __shared__ float s_sc[SS];
  __shared__ float s_part[4][128];          // 2 KB
  __shared__ unsigned s_at2[64];

  const int tid = threadIdx.x;
  const int p = blockIdx.x & 15;
  const int g = blockIdx.x >> 4;
  const int b0 = 2 * p, b1 = 2 * p + 1;
  const int lane = tid & 63;   // = jj for ph1 dots
  const int wv = tid >> 6;     // = i-slice
  const int jglob = g * 64 + lane;

  // ---- one-time staging (t-invariant) ----
  for (int c = 0; c < 2; ++c) {
    const int b = b0 + c;
    for (int idx = tid; idx < 3 * 64 * 64; idx += 512) {
      int gt = idx >> 12, j2 = (idx >> 6) & 63, sp = idx & 63;
      int col = gt * HH + g * 64 + j2;
      unsigned lo = encW[((size_t)b * SS + 2 * sp) * G3 + col];
      unsigned hi = encW[((size_t)b * SS + 2 * sp + 1) * G3 + col];
      s_encw[c][gt][j2][sp ^ (j2 & 31)] = lo | (hi << 16);
    }
    for (int idx = tid; idx < SS * 32; idx += 512) {
      int s = idx >> 5, q = idx & 31;
      s_ep[c][s][q] = ep32[((size_t)b * SS + s) * 256 + g * 32 + q];
    }
  }
  if (tid < 32)
    s_vw2[tid] = packh2(val_w[g * 64 + 2 * tid], val_w[g * 64 + 2 * tid + 1]);
  float bhh0 = 0.f, bhh1 = 0.f, bhh2 = 0.f;
  float hprevA = 0.f, hprevB = 0.f;
  if (tid < 64) {
    bhh0 = b_hh[g * 64 + tid];
    bhh1 = b_hh[HH + g * 64 + tid];
    bhh2 = b_hh[2 * HH + g * 64 + tid];
    hprevA = enc_hidden[(size_t)b0 * HH + g * 64 + tid];
    hprevB = enc_hidden[(size_t)b1 * HH + g * 64 + tid];
  }
  __syncthreads();

  unsigned long long* hxA = hx + (size_t)b0 * 256;
  unsigned long long* hxB = hx + (size_t)b1 * 256;
  unsigned long long* psA = ps + (size_t)b0 * 512;
  unsigned long long* psB = ps + (size_t)b1 * 512;

  const unsigned* wa = (const unsigned*)(wa_t + (size_t)jglob * HH) + wv * 32;
  const unsigned* w0 = (const unsigned*)(whh_h + (size_t)jglob * HH) + wv * 32;
  const unsigned* w1 = (const unsigned*)(whh_h + (size_t)(HH + jglob) * HH) + wv * 32;
  const unsigned* w2 = (const unsigned*)(whh_h + (size_t)(2 * HH + jglob) * HH) + wv * 32;

  float ghrA = 0.f, ghzA = 0.f, ghnA = 0.f;
  float ghrB = 0.f, ghzB = 0.f, ghnB = 0.f;

  // ---- ph1: poll h -> dots -> gh(regs)+hWa -> partial scores -> publish ps --
  auto ph1 = [&](unsigned t, const unsigned long long* hxb,
                 unsigned long long* psb, const unsigned (*sep)[33],
                 float& ghr, float& ghz, float& ghn) {
    unsigned hpair;
    {
      const unsigned long long* src = hxb + wv * 32 + (lane & 31);
      unsigned long long v;
      for (;;) {
        v = ald64(src);
        if (__all((unsigned)(v >> 32) == t)) break;
        __builtin_amdgcn_s_sleep(1);
      }
      hpair = (unsigned)v;
    }
    {
      float a0 = 0.f, a1 = 0.f, a2 = 0.f, a3 = 0.f;
#pragma unroll
      for (int p4 = 0; p4 < 8; ++p4) {
        uint4 va = *(const uint4*)(wa + 4 * p4);
        uint4 v0 = *(const uint4*)(w0 + 4 * p4);
        uint4 v1 = *(const uint4*)(w1 + 4 * p4);
        uint4 v2 = *(const uint4*)(w2 + 4 * p4);
        unsigned h0 = __shfl(hpair, 4 * p4 + 0);
        unsigned h1 = __shfl(hpair, 4 * p4 + 1);
        unsigned h2 = __shfl(hpair, 4 * p4 + 2);
        unsigned h3 = __shfl(hpair, 4 * p4 + 3);
        a0 = fdot2(h0, va.x, a0); a0 = fdot2(h1, va.y, a0);
        a0 = fdot2(h2, va.z, a0); a0 = fdot2(h3, va.w, a0);
        a1 = fdot2(h0, v0.x, a1); a1 = fdot2(h1, v0.y, a1);
        a1 = fdot2(h2, v0.z, a1); a1 = fdot2(h3, v0.w, a1);
        a2 = fdot2(h0, v1.x, a2); a2 = fdot2(h1, v1.y, a2);
        a2 = fdot2(h2, v1.z, a2); a2 = fdot2(h3, v1.w, a2);
        a3 = fdot2(h0, v2.x, a3); a3 = fdot2(h1, v2.y, a3);
        a3 = fdot2(h2, v2.z, a3); a3 = fdot2(h3, v2.w, a3);
      }
      s_p[0][wv][lane] = a0;
      s_p[1][wv][lane] = a1;
      s_p[2][wv][lane] = a2;
      s_p[3][wv][lane] = a3;
    }
    __syncthreads();
    if (tid < 64) {
      float hw = 0.f, r = 0.f, z = 0.f, n = 0.f;
#pragma unroll
      for (int s8 = 0; s8 < 8; ++s8) {
        hw += s_p[0][s8][tid];
        r  += s_p[1][s8][tid];
        z  += s_p[2][s8][tid];
        n  += s_p[3][s8][tid];
      }
      ghr = r + bhh0; ghz = z + bhh1; ghn = n + bhh2;
      float o = __shfl_xor(hw, 1);
      if (!(tid & 1)) s_hwa2[tid >> 1] = packh2(hw, o);
    }
    __syncthreads();
    {
      const int s_ = tid >> 2, q = tid & 3;
      float a0 = 0.f;
#pragma unroll
      for (int pp = 0; pp < 8; ++pp) {
        unsigned v  = sep[s_][q * 8 + pp];
        unsigned hh = s_hwa2[q * 8 + pp];
        unsigned vv = s_vw2[q * 8 + pp];
        a0 = fmaf(tanh_f(h2lo(v) + h2lo(hh)), h2lo(vv), a0);
        a0 = fmaf(tanh_f(h2hi(v) + h2hi(hh)), h2hi(vv), a0);
      }
      a0 += __shfl_xor(a0, 1);
      a0 += __shfl_xor(a0, 2);
      float nb = __shfl_down(a0, 4);
      if ((tid & 7) == 0)
        ast64(psb + g * 64 + (s_ >> 1), mkchunk(packh2(a0, nb), t + 1));
    }
  };

  // ---- ph2: poll ps -> softmax -> weighted(global enc) || gates -> pub h ----
  auto ph2 = [&](unsigned t, int b, unsigned long long* psb,
                 unsigned long long* hxb, const unsigned (*sencw)[64][64],
                 float ghr, float ghz, float ghn, float& hprev) {
    {
      const int pg = tid >> 6, pc = tid & 63;
      unsigned long long v;
      for (;;) {
        v = ald64(psb + pg * 64 + pc);
        if ((unsigned)(v >> 32) == t + 1) break;
        __builtin_amdgcn_s_sleep(1);
      }
      s_ps[pg][pc] = (unsigned)v;
    }
    __syncthreads();
    if (tid < 64) {
      float v0 = 0.f, v1 = 0.f;
#pragma unroll
      for (int gg = 0; gg < 8; ++gg) {
        unsigned q = s_ps[gg][tid];
        v0 += h2lo(q);
        v1 += h2hi(q);
      }
      float m = fmaxf(v0, v1);
#pragma unroll
      for (int mm = 32; mm >= 1; mm >>= 1) m = fmaxf(m, __shfl_xor(m, mm));
      float e0 = __expf(v0 - m), e1 = __expf(v1 - m);
      float sum = e0 + e1;
#pragma unroll
      for (int mm = 32; mm >= 1; mm >>= 1) sum += __shfl_xor(sum, mm);
      float rs = fast_rcp(sum);
      e0 *= rs; e1 *= rs;
      s_sc[2 * tid] = e0;
      s_sc[2 * tid + 1] = e1;
      s_at2[tid] = packh2(e0, e1);
    }
    __syncthreads();
    if (tid < 64) {  // gates -> h_new -> publish
      float a0 = 0.f, a1 = 0.f, a2 = 0.f;
#pragma unroll 8
      for (int sp = 0; sp < 64; ++sp) {
        unsigned at = s_at2[sp];
        const int sx = sp ^ (tid & 31);
        a0 = fdot2(at, sencw[0][tid][sx], a0);
        a1 = fdot2(at, sencw[1][tid][sx], a1);
        a2 = fdot2(at, sencw[2][tid][sx], a2);
      }
      const unsigned short* geb = geh + (size_t)(b * TT + t) * G3 + jglob;
      float r = sigmoid_f(a0 + u16tof(geb[0]) + ghr);
      float z = sigmoid_f(a1 + u16tof(geb[HH]) + ghz);
      float nn = tanh_f(a2 + u16tof(geb[2 * HH]) + r * ghn);
      float hnew = (1.f - z) * nn + z * hprev;
      hprev = hnew;
      Xh[(size_t)(b * TT + t) * CIN + jglob] = f2h(hnew);
      float o = __shfl_xor(hnew, 1);
      if (!(tid & 1))
        ast64(hxb + g * 32 + (tid >> 1), mkchunk(packh2(hnew, o), t + 1));
    } else if (tid >= 256) {  // weighted partials, enc from L2
      const int qs = (tid - 256) >> 6, ep2 = tid & 63;
      const unsigned* eb = enc32 + ((size_t)b * SS + qs * 32) * 512 + g * 64 + ep2;
      float w0v = 0.f, w1v = 0.f;
#pragma unroll 8
      for (int s = 0; s < 32; ++s) {
        unsigned v = eb[(size_t)s * 512];
        float a = s_sc[qs * 32 + s];
        w0v = fmaf(a, h2lo(v), w0v);
        w1v = fmaf(a, h2hi(v), w1v);
      }
      s_part[qs][2 * ep2]     = w0v;
      s_part[qs][2 * ep2 + 1] = w1v;
    }
    __syncthreads();
    if (tid >= 128 && tid < 256) {
      const int e = tid - 128;
      float w = s_part[0][e] + s_part[1][e] + s_part[2][e] + s_part[3][e];
      Xh[(size_t)(b * TT + t) * CIN + HH + g * 128 + e] = f2h(w);
    }
    __syncthreads();  // boundary before next phase reuses transients
  };

  for (unsigned t = 0; t < TT; ++t) {
    ph1(t, hxA, psA, s_ep[0], ghrA, ghzA, ghnA);
    ph1(t, hxB, psB, s_ep[1], ghrB, ghzB, ghnB);   // hides psA's RT
    ph2(t, b0, psA, hxA, s_encw[0], ghrA, ghzA, ghnA, hprevA);  // hides psB RT
    ph2(t, b1, psB, hxB, s_encw[1], ghrB, ghzB, ghnB, hprevB);  // hides hA RT
  }
}

extern "C" void kernel_launch(void* const* d_in, const int* in_sizes, int n_in,
                              void* d_out, int out_size, void* d_ws, size_t ws_size,
                              hipStream_t stream) {
  (void)in_sizes; (void)n_in; (void)out_size; (void)ws_size;
  const int* input_ids = (const int*)d_in[0];
  // d_in[1] attention_mask: all ones
  const float* enc_hidden  = (const float*)d_in[2];
  const float* enc_outputs = (const float*)d_in[3];
  const float* embed_W = (const float*)d_in[4];
  const float* attn_W  = (const float*)d_in[5];
  const float* attn_b  = (const float*)d_in[6];
  const float* val_w   = (const float*)d_in[7];
  const float* W_ih    = (const float*)d_in[8];
  const float* W_hh    = (const float*)d_in[9];
  const float* b_ih    = (const float*)d_in[10];
  const float* b_hh    = (const float*)d_in[11];
  const float* fc_W    = (const float*)d_in[12];
  const float* fc_b    = (const float*)d_in[13];
  float* out = (float*)d_out;

  char* wsb = (char*)d_ws;
  unsigned short* Xh      = (unsigned short*)wsb; wsb += (size_t)BB*TT*CIN*2;
  unsigned short* geh     = (unsigned short*)wsb; wsb += (size_t)BB*TT*G3*2;
  unsigned short* enc_h   = (unsigned short*)wsb; wsb += (size_t)BB*SS*EE*2;
  unsigned short* ep_h    = (unsigned short*)wsb; wsb += (size_t)BB*SS*HH*2;
  unsigned short* wihw_h  = (unsigned short*)wsb; wsb += (size_t)G3*EE*2;
  unsigned short* encW    = (unsigned short*)wsb; wsb += (size_t)BB*SS*G3*2;
  unsigned short* whh_h   = (unsigned short*)wsb; wsb += (size_t)G3*HH*2;
  unsigned short* wa_t    = (unsigned short*)wsb; wsb += (size_t)HH*HH*2;
  unsigned short* waet    = (unsigned short*)wsb; wsb += (size_t)HH*EE*2;
  unsigned short* wih768  = (unsigned short*)wsb; wsb += (size_t)G3*DD*2;
  unsigned short* fcw_h   = (unsigned short*)wsb; wsb += (size_t)DD*CIN*2;
  unsigned long long* hx  = (unsigned long long*)wsb; wsb += (size_t)BB*256*8;
  unsigned long long* ps  = (unsigned long long*)wsb; wsb += (size_t)BB*512*8;

  // ---- 1: fused prep (re-inits hx seqs, zeroes ps each call) ----
  prep_kernel<<<PB8, 256, 0, stream>>>(
      input_ids, embed_W, enc_hidden, enc_outputs, attn_W, W_ih, W_hh, fc_W,
      Xh, enc_h, whh_h, fcw_h, wih768, wihw_h, wa_t, waet, hx, ps);

  // ---- 2: fused pre-GEMMs (ep | geh | encW) ----
  gemm3_kernel<<<704, 256, 0, stream>>>(
      enc_h, waet, attn_b, ep_h, Xh, wih768, b_ih, geh, wihw_h, encW);

  // ---- 3: persistent recurrence (dual-chain interleave, 128 blocks) ----
  void* args[] = {
      (void*)&wa_t, (void*)&whh_h, (void*)&val_w, (void*)&b_hh,
      (void*)&ep_h, (void*)&enc_h, (void*)&encW, (void*)&geh, (void*)&enc_hidden,
      (void*)&hx, (void*)&ps, (void*)&Xh};
  hipLaunchCooperativeKernel((void*)recur_kernel, dim3(128), dim3(512),
                             args, 0, stream);

  // ---- 4: all preds in one MFMA GEMM ----
  out_gemm_kernel<<<dim3(DD / 128, (BB * TT) / 128), 256, 0, stream>>>(
      Xh, fcw_h, fc_b, out);
}

// Round 17
// 592.686 us; speedup vs baseline: 1.9327x; 1.9327x over previous
//
#include <hip/hip_runtime.h>

// Seq2SeqDecoder GRU+attention decoder, B=32 T=64 S=128.
// FINAL (= R13, measured best 591us): 32 groups x 8 blocks; poll-on-data
// exchange (8B {f16-pair,seq} agent chunks, zero barrier constructs);
// j-partitioned partial scores; LDS-resident encW/ep/enc slices; all
// pre/post GEMMs MFMA f16 with 2-deep register prefetch; 4 dispatches total.
//
// Structural floor note: the 64-step recurrence pays 2 cross-CU exchange
// round-trips per step (~1.5-2us each at the agent coherence point). All
// faster exchange scopes tried (sc0 L2 mailbox) are not coherently visible
// cross-CU on gfx950; all barrier variants converge to the same floor.

constexpr int BB  = 32;
constexpr int TT  = 64;
constexpr int SS  = 128;
constexpr int DD  = 768;
constexpr int EE  = 1024;
constexpr int HH  = 512;
constexpr int G3  = 1536;
constexpr int II  = 1792;   // E2 + D
constexpr int CIN = 2304;   // H + E2 + D
constexpr int NBLK = 256;

typedef _Float16 half2_t __attribute__((ext_vector_type(2)));
typedef _Float16 half8_t __attribute__((ext_vector_type(8)));
typedef float f32x4_t __attribute__((ext_vector_type(4)));

__device__ __forceinline__ float fast_rcp(float x) { return __builtin_amdgcn_rcpf(x); }
__device__ __forceinline__ float tanh_f(float x) {
  float e = __expf(2.f * x);
  return 1.f - 2.f * fast_rcp(1.f + e);
}
__device__ __forceinline__ float sigmoid_f(float x) { return fast_rcp(1.f + __expf(-x)); }
__device__ __forceinline__ unsigned packh2(float x, float y) {
  half2_t h; h[0] = (_Float16)x; h[1] = (_Float16)y;
  return __builtin_bit_cast(unsigned, h);
}
__device__ __forceinline__ float h2lo(unsigned v) {
  return (float)__builtin_bit_cast(half2_t, v)[0];
}
__device__ __forceinline__ float h2hi(unsigned v) {
  return (float)__builtin_bit_cast(half2_t, v)[1];
}
__device__ __forceinline__ unsigned short f2h(float f) {
  _Float16 h = (_Float16)f; return __builtin_bit_cast(unsigned short, h);
}
__device__ __forceinline__ float u16tof(unsigned short u) {
  return (float)__builtin_bit_cast(_Float16, u);
}
__device__ __forceinline__ float fdot2(unsigned a, unsigned b, float c) {
#if __has_builtin(__builtin_amdgcn_fdot2)
  return __builtin_amdgcn_fdot2(__builtin_bit_cast(half2_t, a),
                                __builtin_bit_cast(half2_t, b), c, false);
#else
  half2_t ha = __builtin_bit_cast(half2_t, a);
  half2_t hb = __builtin_bit_cast(half2_t, b);
  return fmaf((float)ha[1], (float)hb[1], fmaf((float)ha[0], (float)hb[0], c));
#endif
}

__device__ __forceinline__ unsigned long long ald64(const unsigned long long* p) {
  return __hip_atomic_load(p, __ATOMIC_RELAXED, __HIP_MEMORY_SCOPE_AGENT);
}
__device__ __forceinline__ void ast64(unsigned long long* p, unsigned long long v) {
  __hip_atomic_store(p, v, __ATOMIC_RELAXED, __HIP_MEMORY_SCOPE_AGENT);
}
__device__ __forceinline__ unsigned long long mkchunk(unsigned pair, unsigned seq) {
  return (unsigned long long)pair | ((unsigned long long)seq << 32);
}

// ================= fused prep kernel ==========================================
constexpr int PB0 = 33;           // hx init (32) + ps zero (1)
constexpr int PB1 = PB0 + 2048;   // emb rows
constexpr int PB2 = PB1 + 2048;   // enc cast
constexpr int PB3 = PB2 + 384;    // whh cast
constexpr int PB4 = PB3 + 864;    // fcw cast
constexpr int PB5 = PB4 + 1536;   // wih768 pack
constexpr int PB6 = PB5 + 1536;   // wihw pack
constexpr int PB7 = PB6 + 256;    // wa tcast
constexpr int PB8 = PB7 + 512;    // waet tcast

__device__ __forceinline__ void cast8(const float* __restrict__ in,
                                      unsigned short* __restrict__ out,
                                      int blk, int tid) {
  int i = (blk * 256 + tid) * 8;
  float4 a = *(const float4*)(in + i);
  float4 b = *(const float4*)(in + i + 4);
  unsigned short r[8] = {f2h(a.x), f2h(a.y), f2h(a.z), f2h(a.w),
                         f2h(b.x), f2h(b.y), f2h(b.z), f2h(b.w)};
  *(uint4*)(out + i) = *(uint4*)r;
}
__device__ __forceinline__ void pack_row(const float* __restrict__ src, int srcld,
                                         unsigned short* __restrict__ dst, int W,
                                         int r, int tid) {
  const float* s = src + (size_t)r * srcld;
  unsigned short* d = dst + (size_t)r * W;
  for (int c = tid * 4; c < W; c += 256 * 4) {
    float4 v = *(const float4*)(s + c);
    unsigned short q[4] = {f2h(v.x), f2h(v.y), f2h(v.z), f2h(v.w)};
    *(unsigned long long*)(d + c) = *(unsigned long long*)q;
  }
}
__device__ __forceinline__ void tcast_tile(const float* __restrict__ in, int R,
                                           int C, unsigned short* __restrict__ out,
                                           int bx, int by, int tid, float (*t)[33]) {
  const int c0 = bx * 32, r0 = by * 32;
  const int tx = tid & 31, ty = tid >> 5;  // 32x8
  for (int dy = 0; dy < 32; dy += 8)
    t[ty + dy][tx] = in[(size_t)(r0 + ty + dy) * C + c0 + tx];
  __syncthreads();
  for (int dy = 0; dy < 32; dy += 8)
    out[(size_t)(c0 + ty + dy) * R + r0 + tx] = f2h(t[tx][ty + dy]);
}

__global__ __launch_bounds__(256) void prep_kernel(
    const int* __restrict__ ids, const float* __restrict__ embed_W,
    const float* __restrict__ enc_hidden, const float* __restrict__ enc_outputs,
    const float* __restrict__ attn_W, const float* __restrict__ W_ih,
    const float* __restrict__ W_hh, const float* __restrict__ fc_W,
    unsigned short* __restrict__ Xh, unsigned short* __restrict__ enc_h,
    unsigned short* __restrict__ whh_h, unsigned short* __restrict__ fcw_h,
    unsigned short* __restrict__ wih768, unsigned short* __restrict__ wihw_h,
    unsigned short* __restrict__ wa_t, unsigned short* __restrict__ waet,
    unsigned long long* __restrict__ hx, unsigned long long* __restrict__ ps)
{
  __shared__ float tbuf[32][33];
  const int bidx = blockIdx.x;
  const int tid = threadIdx.x;
  if (bidx < PB0) {
    int b = bidx;
    if (b < BB) {
      unsigned pair = packh2(enc_hidden[(size_t)b * HH + 2 * tid],
                             enc_hidden[(size_t)b * HH + 2 * tid + 1]);
      hx[(size_t)b * 256 + tid] = mkchunk(pair, 0u);
    } else {
      for (int i = tid; i < BB * 8 * 64; i += 256) ps[i] = 0ull;
    }
  } else if (bidx < PB1) {
    int row = bidx - PB0;
    int id = ids[row];                       // attention_mask all-ones
    const float scale = 27.712812921102035f; // sqrt(768)
    const float* src = embed_W + (size_t)id * DD;
    unsigned short* dst = Xh + (size_t)row * CIN + (HH + EE);
    for (int c = tid; c < DD; c += 256) dst[c] = f2h(src[c] * scale);
  } else if (bidx < PB2) {
    cast8(enc_outputs, enc_h, bidx - PB1, tid);
  } else if (bidx < PB3) {
    cast8(W_hh, whh_h, bidx - PB2, tid);
  } else if (bidx < PB4) {
    cast8(fc_W, fcw_h, bidx - PB3, tid);
  } else if (bidx < PB5) {
    pack_row(W_ih, II, wih768, DD, bidx - PB4, tid);
  } else if (bidx < PB6) {
    pack_row(W_ih + DD, II, wihw_h, EE, bidx - PB5, tid);
  } else if (bidx < PB7) {
    int q = bidx - PB6;
    tcast_tile(attn_W, HH, HH, wa_t, q & 15, q >> 4, tid, tbuf);
  } else {
    int q = bidx - PB7;
    tcast_tile(attn_W + (size_t)HH * HH, EE, HH, waet, q & 15, q >> 4, tid, tbuf);
  }
}

// ========== MFMA f16 128x128 tile, 2-deep register prefetch ===================
template <bool F32OUT>
__device__ __forceinline__ void mfma_tile128(
    const unsigned short* __restrict__ Ah, int lda,
    const unsigned short* __restrict__ Bh, int ldb,
    const float* __restrict__ bias,
    unsigned short* __restrict__ Ch, float* __restrict__ Cf, int ldc, int K,
    int m0, int n0)
{
  const int lane = threadIdx.x & 63;
  const int wv = threadIdx.x >> 6;
  const int wr = wv >> 1, wc = wv & 1;          // 2x2 wave grid, 64x64 each
  const int rbase = m0 + wr * 64 + (lane & 15);
  const int cbase = n0 + wc * 64 + (lane & 15);
  const int koff = (lane >> 4) * 8;
  f32x4_t acc[4][4] = {};
  half8_t a[4], b[4];
#pragma unroll
  for (int i = 0; i < 4; ++i) {
    a[i] = *(const half8_t*)(Ah + (size_t)(rbase + i * 16) * lda + koff);
    b[i] = *(const half8_t*)(Bh + (size_t)(cbase + i * 16) * ldb + koff);
  }
  for (int k0 = 32; k0 < K; k0 += 32) {
    half8_t an[4], bn[4];
#pragma unroll
    for (int i = 0; i < 4; ++i) {
      an[i] = *(const half8_t*)(Ah + (size_t)(rbase + i * 16) * lda + k0 + koff);
      bn[i] = *(const half8_t*)(Bh + (size_t)(cbase + i * 16) * ldb + k0 + koff);
    }
#pragma unroll
    for (int mf = 0; mf < 4; ++mf)
#pragma unroll
      for (int nf = 0; nf < 4; ++nf)
        acc[mf][nf] =
            __builtin_amdgcn_mfma_f32_16x16x32_f16(a[mf], b[nf], acc[mf][nf], 0, 0, 0);
#pragma unroll
    for (int i = 0; i < 4; ++i) { a[i] = an[i]; b[i] = bn[i]; }
  }
#pragma unroll
  for (int mf = 0; mf < 4; ++mf)
#pragma unroll
    for (int nf = 0; nf < 4; ++nf)
      acc[mf][nf] =
          __builtin_amdgcn_mfma_f32_16x16x32_f16(a[mf], b[nf], acc[mf][nf], 0, 0, 0);
#pragma unroll
  for (int mf = 0; mf < 4; ++mf)
#pragma unroll
    for (int nf = 0; nf < 4; ++nf) {
      const int col = n0 + wc * 64 + nf * 16 + (lane & 15);
      const float bv = bias ? bias[col] : 0.f;
#pragma unroll
      for (int r = 0; r < 4; ++r) {
        const int rr = m0 + wr * 64 + mf * 16 + (lane >> 4) * 4 + r;
        if (F32OUT) Cf[(size_t)rr * ldc + col] = acc[mf][nf][r] + bv;
        else        Ch[(size_t)rr * ldc + col] = f2h(acc[mf][nf][r] + bv);
      }
    }
}

// fused pre-GEMMs: ep (128 blocks) | geh (192) | encW (384)
__global__ __launch_bounds__(256) void gemm3_kernel(
    const unsigned short* __restrict__ enc_h,
    const unsigned short* __restrict__ waet,
    const float* __restrict__ attn_b,
    unsigned short* __restrict__ ep_h,
    const unsigned short* __restrict__ Xh,
    const unsigned short* __restrict__ wih768,
    const float* __restrict__ b_ih,
    unsigned short* __restrict__ geh,
    const unsigned short* __restrict__ wihw_h,
    unsigned short* __restrict__ encW)
{
  const int id = blockIdx.x;
  if (id < 128) {               // ep: M=4096 N=512 K=1024 -> 32m x 4n
    int nt = id & 3, mt = id >> 2;
    mfma_tile128<false>(enc_h, EE, waet, EE, attn_b, ep_h, nullptr, HH, EE,
                        mt * 128, nt * 128);
  } else if (id < 320) {        // geh: M=2048 N=1536 K=768 -> 16m x 12n
    int q = id - 128, nt = q % 12, mt = q / 12;
    mfma_tile128<false>(Xh + (HH + EE), CIN, wih768, DD, b_ih, geh, nullptr,
                        G3, DD, mt * 128, nt * 128);
  } else {                      // encW: M=4096 N=1536 K=1024 -> 32m x 12n
    int q = id - 320, nt = q % 12, mt = q / 12;
    mfma_tile128<false>(enc_h, EE, wihw_h, EE, nullptr, encW, nullptr,
                        G3, EE, mt * 128, nt * 128);
  }
}

__global__ __launch_bounds__(256) void out_gemm_kernel(
    const unsigned short* __restrict__ Xh,
    const unsigned short* __restrict__ fcw_h,
    const float* __restrict__ fc_b, float* __restrict__ out)
{
  mfma_tile128<true>(Xh, CIN, fcw_h, CIN, fc_b, nullptr, out, DD, CIN,
                     blockIdx.y * 128, blockIdx.x * 128);
}

// ================= persistent recurrence ======================================
// 32 groups x 8 blocks (b=bid&31, g=bid>>5). Block owns j-slice [64g,+64).
// NO barriers: exchanges are 8B {pair,seq} chunks, readers poll seq==target.
//   hx[(b*8+g)*32 + c]: h pair (global pair idx g*32+c); seq = t (h for step t).
//   ps[(b*8+g)*64 + c]: partial-score pair (s=2c,2c+1);   seq = t+1.
__global__ __launch_bounds__(512, 1) void recur_kernel(
    const unsigned short* __restrict__ wa_t,   // [512 j][512 i] f16
    const unsigned short* __restrict__ whh_h,  // [1536 j'][512 i] f16
    const float* __restrict__ val_w,
    const float* __restrict__ b_hh,
    const unsigned* __restrict__ ep32,     // [B*S][256] f16 pairs (proj+attn_b)
    const unsigned* __restrict__ enc32,    // [B*S][512] f16 pairs
    const unsigned short* __restrict__ encW, // [B*S][1536] f16
    const unsigned short* __restrict__ geh,  // [B*T][1536] f16
    const float* __restrict__ enc_hidden,  // (B,H) f32
    unsigned long long* __restrict__ hx,   // [B][8][32] chunks [AGENT]
    unsigned long long* __restrict__ ps,   // [B][8][64] chunks [AGENT]
    unsigned short* __restrict__ Xh)       // [B*T][2304] f16 [h|wtd|emb]
{
  __shared__ unsigned s_encw[3][64][64];   // 48 KB, xor-swizzled on sp
  __shared__ unsigned s_ep[SS][33];        // 16.9 KB (padded rows)
  __shared__ unsigned s_enc[SS][64];       // 32 KB e-slice pairs
  __shared__ float s_p[4][8][64];          // 8 KB ph1 partials
  __shared__ unsigned s_hwa2[32];          // own hWa slice (pairs)
  __shared__ unsigned s_vw2[32];
  __shared__ unsigned s_ps[8][64];         // gathered partial pairs
  __shared__ float s_sc[SS];               // normalized attn
  __shared__ float s_part[4][128];
  __shared__ unsigned s_at2[64];

  const int tid = threadIdx.x;
  const int b = blockIdx.x & 31;
  const int g = blockIdx.x >> 5;
  const int lane = tid & 63;   // = jj for ph1 dots
  const int wv = tid >> 6;     // = i-slice (sub)
  const int jglob = g * 64 + lane;

  // ---- one-time staging (t-invariant) ----
  for (int idx = tid; idx < 3 * 64 * 64; idx += 512) {
    int gt = idx >> 12, j2 = (idx >> 6) & 63, sp = idx & 63;
    int col = gt * HH + g * 64 + j2;
    unsigned lo = encW[((size_t)b * SS + 2 * sp) * G3 + col];
    unsigned hi = encW[((size_t)b * SS + 2 * sp + 1) * G3 + col];
    s_encw[gt][j2][sp ^ (j2 & 31)] = lo | (hi << 16);
  }
  for (int idx = tid; idx < SS * 32; idx += 512) {
    int s = idx >> 5, p = idx & 31;
    s_ep[s][p] = ep32[((size_t)b * SS + s) * 256 + g * 32 + p];
  }
  for (int idx = tid; idx < SS * 64; idx += 512) {
    int s = idx >> 6, p = idx & 63;
    s_enc[s][p] = enc32[((size_t)b * SS + s) * 512 + g * 64 + p];
  }
  if (tid < 32)
    s_vw2[tid] = packh2(val_w[g * 64 + 2 * tid], val_w[g * 64 + 2 * tid + 1]);
  float bhh0 = 0.f, bhh1 = 0.f, bhh2 = 0.f, hprev = 0.f;
  if (tid < 64) {
    bhh0 = b_hh[g * 64 + tid];
    bhh1 = b_hh[HH + g * 64 + tid];
    bhh2 = b_hh[2 * HH + g * 64 + tid];
    hprev = enc_hidden[(size_t)b * HH + g * 64 + tid];
  }
  __syncthreads();

  unsigned long long* hxb = hx + (size_t)b * 256;   // [g][c] = [8][32]
  unsigned long long* psb = ps + (size_t)b * 512;   // [g][c] = [8][64]

  // weight pointers for ph1 (wave wv = i-slice, lane = j)
  const unsigned* wa = (const unsigned*)(wa_t + (size_t)jglob * HH) + wv * 32;
  const unsigned* w0 = (const unsigned*)(whh_h + (size_t)jglob * HH) + wv * 32;
  const unsigned* w1 = (const unsigned*)(whh_h + (size_t)(HH + jglob) * HH) + wv * 32;
  const unsigned* w2 = (const unsigned*)(whh_h + (size_t)(2 * HH + jglob) * HH) + wv * 32;

  for (unsigned t = 0; t < TT; ++t) {
    // ===== ph1: per-wave h-poll + dots + reduce + scores + ps-publish =======
    unsigned hpair;
    {
      const unsigned long long* src = hxb + wv * 32 + (lane & 31);
      unsigned long long v;
      for (;;) {
        v = ald64(src);
        if (__all((unsigned)(v >> 32) == t)) break;
        __builtin_amdgcn_s_sleep(1);
      }
      hpair = (unsigned)v;
    }
    {
      float a0 = 0.f, a1 = 0.f, a2 = 0.f, a3 = 0.f;
#pragma unroll
      for (int p4 = 0; p4 < 8; ++p4) {
        uint4 va = *(const uint4*)(wa + 4 * p4);
        uint4 v0 = *(const uint4*)(w0 + 4 * p4);
        uint4 v1 = *(const uint4*)(w1 + 4 * p4);
        uint4 v2 = *(const uint4*)(w2 + 4 * p4);
        unsigned h0 = __shfl(hpair, 4 * p4 + 0);
        unsigned h1 = __shfl(hpair, 4 * p4 + 1);
        unsigned h2 = __shfl(hpair, 4 * p4 + 2);
        unsigned h3 = __shfl(hpair, 4 * p4 + 3);
        a0 = fdot2(h0, va.x, a0); a0 = fdot2(h1, va.y, a0);
        a0 = fdot2(h2, va.z, a0); a0 = fdot2(h3, va.w, a0);
        a1 = fdot2(h0, v0.x, a1); a1 = fdot2(h1, v0.y, a1);
        a1 = fdot2(h2, v0.z, a1); a1 = fdot2(h3, v0.w, a1);
        a2 = fdot2(h0, v1.x, a2); a2 = fdot2(h1, v1.y, a2);
        a2 = fdot2(h2, v1.z, a2); a2 = fdot2(h3, v1.w, a2);
        a3 = fdot2(h0, v2.x, a3); a3 = fdot2(h1, v2.y, a3);
        a3 = fdot2(h2, v2.z, a3); a3 = fdot2(h3, v2.w, a3);
      }
      s_p[0][wv][lane] = a0;
      s_p[1][wv][lane] = a1;
      s_p[2][wv][lane] = a2;
      s_p[3][wv][lane] = a3;
    }
    __syncthreads();
    float ghr = 0.f, ghz = 0.f, ghn = 0.f;
    if (tid < 64) {
      float hw = 0.f;
#pragma unroll
      for (int s8 = 0; s8 < 8; ++s8) {
        hw  += s_p[0][s8][tid];
        ghr += s_p[1][s8][tid];
        ghz += s_p[2][s8][tid];
        ghn += s_p[3][s8][tid];
      }
      ghr += bhh0; ghz += bhh1; ghn += bhh2;
      float o = __shfl_xor(hw, 1);
      if (!(tid & 1)) s_hwa2[tid >> 1] = packh2(hw, o);
    }
    __syncthreads();
    {  // partial scores over own j-slice, shuffle-publish ps chunks
      const int s_ = tid >> 2, q = tid & 3;
      float a0 = 0.f;
#pragma unroll
      for (int p = 0; p < 8; ++p) {
        unsigned v  = s_ep[s_][q * 8 + p];
        unsigned hh = s_hwa2[q * 8 + p];
        unsigned vv = s_vw2[q * 8 + p];
        a0 = fmaf(tanh_f(h2lo(v) + h2lo(hh)), h2lo(vv), a0);
        a0 = fmaf(tanh_f(h2hi(v) + h2hi(hh)), h2hi(vv), a0);
      }
      a0 += __shfl_xor(a0, 1);
      a0 += __shfl_xor(a0, 2);
      float nb = __shfl_down(a0, 4);  // score s_+1 (same wave, q=0 lane)
      if ((tid & 7) == 0)
        ast64(psb + g * 64 + (s_ >> 1), mkchunk(packh2(a0, nb), t + 1));
    }

    // ===== ph2: poll ps -> softmax -> weighted || gates -> final sum ========
    {
      const int pg = tid >> 6, pc = tid & 63;
      unsigned long long v;
      for (;;) {
        v = ald64(psb + pg * 64 + pc);
        if ((unsigned)(v >> 32) == t + 1) break;
        __builtin_amdgcn_s_sleep(1);
      }
      s_ps[pg][pc] = (unsigned)v;
    }
    __syncthreads();
    if (tid < 64) {  // single-wave softmax; lane L handles scores 2L, 2L+1
      float v0 = 0.f, v1 = 0.f;
#pragma unroll
      for (int gg = 0; gg < 8; ++gg) {
        unsigned p = s_ps[gg][tid];
        v0 += h2lo(p);
        v1 += h2hi(p);
      }
      float m = fmaxf(v0, v1);
#pragma unroll
      for (int mm = 32; mm >= 1; mm >>= 1) m = fmaxf(m, __shfl_xor(m, mm));
      float e0 = __expf(v0 - m), e1 = __expf(v1 - m);
      float sum = e0 + e1;
#pragma unroll
      for (int mm = 32; mm >= 1; mm >>= 1) sum += __shfl_xor(sum, mm);
      float rs = fast_rcp(sum);
      e0 *= rs; e1 *= rs;
      s_sc[2 * tid] = e0;
      s_sc[2 * tid + 1] = e1;
      s_at2[tid] = packh2(e0, e1);
    }
    __syncthreads();
    if (tid < 64) {  // gates (reads only wave-0-written s_at2) -> publish h
      float a0 = 0.f, a1 = 0.f, a2 = 0.f;
#pragma unroll 8
      for (int sp = 0; sp < 64; ++sp) {
        unsigned at = s_at2[sp];
        const int sx = sp ^ (tid & 31);
        a0 = fdot2(at, s_encw[0][tid][sx], a0);
        a1 = fdot2(at, s_encw[1][tid][sx], a1);
        a2 = fdot2(at, s_encw[2][tid][sx], a2);
      }
      const unsigned short* geb = geh + (size_t)(b * TT + t) * G3 + jglob;
      float r = sigmoid_f(a0 + u16tof(geb[0]) + ghr);
      float z = sigmoid_f(a1 + u16tof(geb[HH]) + ghz);
      float nn = tanh_f(a2 + u16tof(geb[2 * HH]) + r * ghn);
      float hnew = (1.f - z) * nn + z * hprev;
      hprev = hnew;
      Xh[(size_t)(b * TT + t) * CIN + jglob] = f2h(hnew);
      float o = __shfl_xor(hnew, 1);
      if (!(tid & 1))
        ast64(hxb + g * 32 + (tid >> 1), mkchunk(packh2(hnew, o), t + 1));
    } else if (tid >= 256) {  // weighted partials from LDS enc slice
      const int qs = (tid - 256) >> 6, ep2 = tid & 63;
      float w0 = 0.f, w1 = 0.f;
#pragma unroll 8
      for (int s = 0; s < 32; ++s) {
        unsigned v = s_enc[qs * 32 + s][ep2];
        float a = s_sc[qs * 32 + s];
        w0 = fmaf(a, h2lo(v), w0);
        w1 = fmaf(a, h2hi(v), w1);
      }
      s_part[qs][2 * ep2]     = w0;
      s_part[qs][2 * ep2 + 1] = w1;
    }
    __syncthreads();
    if (tid >= 128 && tid < 256) {  // final weighted sum -> Xh
      const int e = tid - 128;
      float w = s_part[0][e] + s_part[1][e] + s_part[2][e] + s_part[3][e];
      Xh[(size_t)(b * TT + t) * CIN + HH + g * 128 + e] = f2h(w);
    }
  }
}

extern "C" void kernel_launch(void* const* d_in, const int* in_sizes, int n_in,
                              void* d_out, int out_size, void* d_ws, size_t ws_size,
                              hipStream_t stream) {
  (void)in_sizes; (void)n_in; (void)out_size; (void)ws_size;
  const int* input_ids = (const int*)d_in[0];
  // d_in[1] attention_mask: all ones
  const float* enc_hidden  = (const float*)d_in[2];
  const float* enc_outputs = (const float*)d_in[3];
  const float* embed_W = (const float*)d_in[4];
  const float* attn_W  = (const float*)d_in[5];
  const float* attn_b  = (const float*)d_in[6];
  const float* val_w   = (const float*)d_in[7];
  const float* W_ih    = (const float*)d_in[8];
  const float* W_hh    = (const float*)d_in[9];
  const float* b_ih    = (const float*)d_in[10];
  const float* b_hh    = (const float*)d_in[11];
  const float* fc_W    = (const float*)d_in[12];
  const float* fc_b    = (const float*)d_in[13];
  float* out = (float*)d_out;

  char* wsb = (char*)d_ws;
  unsigned short* Xh      = (unsigned short*)wsb; wsb += (size_t)BB*TT*CIN*2;
  unsigned short* geh     = (unsigned short*)wsb; wsb += (size_t)BB*TT*G3*2;
  unsigned short* enc_h   = (unsigned short*)wsb; wsb += (size_t)BB*SS*EE*2;
  unsigned short* ep_h    = (unsigned short*)wsb; wsb += (size_t)BB*SS*HH*2;
  unsigned short* wihw_h  = (unsigned short*)wsb; wsb += (size_t)G3*EE*2;
  unsigned short* encW    = (unsigned short*)wsb; wsb += (size_t)BB*SS*G3*2;
  unsigned short* whh_h   = (unsigned short*)wsb; wsb += (size_t)G3*HH*2;
  unsigned short* wa_t    = (unsigned short*)wsb; wsb += (size_t)HH*HH*2;
  unsigned short* waet    = (unsigned short*)wsb; wsb += (size_t)HH*EE*2;
  unsigned short* wih768  = (unsigned short*)wsb; wsb += (size_t)G3*DD*2;
  unsigned short* fcw_h   = (unsigned short*)wsb; wsb += (size_t)DD*CIN*2;
  unsigned long long* hx  = (unsigned long long*)wsb; wsb += (size_t)BB*256*8;
  unsigned long long* ps  = (unsigned long long*)wsb; wsb += (size_t)BB*512*8;

  // ---- 1: fused prep (re-inits hx seqs, zeroes ps each call) ----
  prep_kernel<<<PB8, 256, 0, stream>>>(
      input_ids, embed_W, enc_hidden, enc_outputs, attn_W, W_ih, W_hh, fc_W,
      Xh, enc_h, whh_h, fcw_h, wih768, wihw_h, wa_t, waet, hx, ps);

  // ---- 2: fused pre-GEMMs (ep | geh | encW), 128x128 tiles ----
  gemm3_kernel<<<704, 256, 0, stream>>>(
      enc_h, waet, attn_b, ep_h, Xh, wih768, b_ih, geh, wihw_h, encW);

  // ---- 3: persistent recurrence (poll-on-data, zero barriers) ----
  void* args[] = {
      (void*)&wa_t, (void*)&whh_h, (void*)&val_w, (void*)&b_hh,
      (void*)&ep_h, (void*)&enc_h, (void*)&encW, (void*)&geh, (void*)&enc_hidden,
      (void*)&hx, (void*)&ps, (void*)&Xh};
  hipLaunchCooperativeKernel((void*)recur_kernel, dim3(NBLK), dim3(512),
                             args, 0, stream);

  // ---- 4: all preds in one MFMA GEMM (128x128 tiles) ----
  out_gemm_kernel<<<dim3(DD / 128, (BB * TT) / 128), 256, 0, stream>>>(
      Xh, fcw_h, fc_b, out);
}